// Round 6
// baseline (388.521 us; speedup 1.0000x reference)
//
#include <hip/hip_runtime.h>
#include <hip/hip_bf16.h>
#include <math.h>
#include <stdint.h>

// Problem constants
#define Bz 8
#define Lz 2048
#define Dz 512
#define KTOP 15

typedef __attribute__((ext_vector_type(8))) unsigned short ushort8x;
typedef __attribute__((ext_vector_type(8))) _Float16 half8x;    // fp16x8 MFMA frag
typedef __attribute__((ext_vector_type(4))) float floatx4;      // fp32x4
typedef __attribute__((ext_vector_type(16))) float floatx16;    // 32x32 MFMA acc

// ---------------------------------------------------------------------------
// Transpose-cast the 3 weight matrices (K x N fp32) -> (N x K fp16), contiguous
// grid (16,16,3), block (32,8)
// ---------------------------------------------------------------------------
__global__ __launch_bounds__(256) void wtrans3(
    const float* __restrict__ w0, const float* __restrict__ w1,
    const float* __restrict__ w2, _Float16* __restrict__ t) {
  const float* w = blockIdx.z == 0 ? w0 : (blockIdx.z == 1 ? w1 : w2);
  _Float16* tz = t + (size_t)blockIdx.z * Dz * Dz;
  __shared__ float tile[32][33];
  const int n0 = blockIdx.x * 32, k0 = blockIdx.y * 32;
  const int tx = threadIdx.x, ty = threadIdx.y;
  #pragma unroll
  for (int i = 0; i < 4; ++i)
    tile[ty + 8 * i][tx] = w[(size_t)(k0 + ty + 8 * i) * Dz + n0 + tx];
  __syncthreads();
  #pragma unroll
  for (int i = 0; i < 4; ++i)
    tz[(size_t)(n0 + ty + 8 * i) * Dz + k0 + tx] = (_Float16)tile[tx][ty + 8 * i];
}

// ---------------------------------------------------------------------------
// Merged MFMA GEMM for q,k,v: z = blockIdx.z selects input/weights/output.
// z<2: write fp16 transposed (B,D,L); z==2: write fp32 natural (B,L,D).
// 128x128 tile, 256 threads (4 waves 2x2), 4x4 frags 16x16x32, BK=32, dbuf.
// ---------------------------------------------------------------------------
#define GLDA 40
__global__ __launch_bounds__(256) void gemm3(
    const float* __restrict__ Qin, const float* __restrict__ Kin,
    const float* __restrict__ Vin, const _Float16* __restrict__ Wt,
    const float* __restrict__ bq, const float* __restrict__ bk,
    const float* __restrict__ bv, _Float16* __restrict__ qT,
    _Float16* __restrict__ kT, float* __restrict__ vout) {
  const int K = Dz, N = Dz;
  const int z = blockIdx.z;
  const float* A = z == 0 ? Qin : (z == 1 ? Kin : Vin);
  const _Float16* Bt = Wt + (size_t)z * Dz * Dz;
  const float* bias = z == 0 ? bq : (z == 1 ? bk : bv);

  __shared__ _Float16 smem[20480];  // 40KB: As[2][5120] | Bs[2][5120]
  _Float16* Asb = smem;
  _Float16* Bsb = smem + 10240;
  const int tid = threadIdx.x;
  const int m0 = blockIdx.y * 128;
  const int n0 = blockIdx.x * 128;
  const int lane = tid & 63;
  const int wv = tid >> 6;
  const int wr = wv & 1, wc = wv >> 1;
  const int ln = lane & 15;
  const int quad = lane >> 4;

  floatx4 acc[4][4];
  #pragma unroll
  for (int i = 0; i < 4; ++i)
    #pragma unroll
    for (int j = 0; j < 4; ++j) acc[i][j] = (floatx4){0.f, 0.f, 0.f, 0.f};

  float4 ra4[4];
  ushort8x rb[2];

  #pragma unroll
  for (int j = 0; j < 4; ++j) {
    const int slot = tid + 256 * j;
    const int r = slot >> 3, c4 = slot & 7;
    ra4[j] = *(const float4*)&A[(size_t)(m0 + r) * K + 4 * c4];
  }
  #pragma unroll
  for (int j = 0; j < 2; ++j) {
    const int slot = tid + 256 * j;
    const int r = slot >> 2, ch = slot & 3;
    rb[j] = *(const ushort8x*)((const unsigned short*)Bt +
                               (size_t)(n0 + r) * K + 8 * ch);
  }
  {
    #pragma unroll
    for (int j = 0; j < 4; ++j) {
      const int slot = tid + 256 * j;
      const int r = slot >> 3, c4 = slot & 7;
      union { _Float16 h[4]; unsigned long long u; } p;
      p.h[0] = (_Float16)ra4[j].x;
      p.h[1] = (_Float16)ra4[j].y;
      p.h[2] = (_Float16)ra4[j].z;
      p.h[3] = (_Float16)ra4[j].w;
      *(unsigned long long*)&Asb[r * GLDA + 4 * c4] = p.u;
    }
    #pragma unroll
    for (int j = 0; j < 2; ++j) {
      const int slot = tid + 256 * j;
      const int r = slot >> 2, ch = slot & 3;
      *(ushort8x*)&Bsb[r * GLDA + 8 * ch] = rb[j];
    }
  }
  __syncthreads();

  const int NKT = K / 32;  // 16
  for (int kt = 0; kt < NKT; ++kt) {
    const int cur = kt & 1;
    if (kt + 1 < NKT) {
      const int kof = (kt + 1) * 32;
      #pragma unroll
      for (int j = 0; j < 4; ++j) {
        const int slot = tid + 256 * j;
        const int r = slot >> 3, c4 = slot & 7;
        ra4[j] = *(const float4*)&A[(size_t)(m0 + r) * K + kof + 4 * c4];
      }
      #pragma unroll
      for (int j = 0; j < 2; ++j) {
        const int slot = tid + 256 * j;
        const int r = slot >> 2, ch = slot & 3;
        rb[j] = *(const ushort8x*)((const unsigned short*)Bt +
                                   (size_t)(n0 + r) * K + kof + 8 * ch);
      }
    }
    const _Float16* As = Asb + cur * 5120;
    const _Float16* Bs = Bsb + cur * 5120;
    half8x af[4], bf[4];
    #pragma unroll
    for (int i = 0; i < 4; ++i)
      af[i] = *(const half8x*)&As[(wr * 64 + 16 * i + ln) * GLDA + 8 * quad];
    #pragma unroll
    for (int j = 0; j < 4; ++j)
      bf[j] = *(const half8x*)&Bs[(wc * 64 + 16 * j + ln) * GLDA + 8 * quad];
    #pragma unroll
    for (int i = 0; i < 4; ++i)
      #pragma unroll
      for (int j = 0; j < 4; ++j)
        acc[i][j] = __builtin_amdgcn_mfma_f32_16x16x32_f16(af[i], bf[j], acc[i][j], 0, 0, 0);
    if (kt + 1 < NKT) {
      const int nxt = cur ^ 1;
      _Float16* Asw = Asb + nxt * 5120;
      _Float16* Bsw = Bsb + nxt * 5120;
      #pragma unroll
      for (int j = 0; j < 4; ++j) {
        const int slot = tid + 256 * j;
        const int r = slot >> 3, c4 = slot & 7;
        union { _Float16 h[4]; unsigned long long u; } p;
        p.h[0] = (_Float16)ra4[j].x;
        p.h[1] = (_Float16)ra4[j].y;
        p.h[2] = (_Float16)ra4[j].z;
        p.h[3] = (_Float16)ra4[j].w;
        *(unsigned long long*)&Asw[r * GLDA + 4 * c4] = p.u;
      }
      #pragma unroll
      for (int j = 0; j < 2; ++j) {
        const int slot = tid + 256 * j;
        const int r = slot >> 2, ch = slot & 3;
        *(ushort8x*)&Bsw[r * GLDA + 8 * ch] = rb[j];
      }
      __syncthreads();
    }
  }

  if (z < 2) {
    // retranspose through LDS, write fp16 (B, D, L)
    __syncthreads();
    _Float16* TB = smem;  // [128][136] = 34816 B
    #pragma unroll
    for (int j = 0; j < 4; ++j) {
      const int n_l = wc * 64 + 16 * j + ln;
      const float bvv = bias[n0 + n_l];
      #pragma unroll
      for (int i = 0; i < 4; ++i) {
        const int m_l = wr * 64 + 16 * i + 4 * quad;
        union { _Float16 h[4]; unsigned long long u; } p;
        #pragma unroll
        for (int r = 0; r < 4; ++r) p.h[r] = (_Float16)(acc[i][j][r] + bvv);
        *(unsigned long long*)&TB[n_l * 136 + m_l] = p.u;
      }
    }
    __syncthreads();
    _Float16* oT = (z == 0 ? qT : kT);
    const int b = m0 >> 11;
    const int l0 = m0 & 2047;
    #pragma unroll
    for (int it = 0; it < 8; ++it) {
      const int s = tid + 256 * it;
      const int n = s >> 4, c = s & 15;
      *(ushort8x*)(oT + ((size_t)(b * Dz + n0 + n)) * Lz + l0 + 8 * c) =
          *(const ushort8x*)&TB[n * 136 + 8 * c];
    }
  } else {
    #pragma unroll
    for (int j = 0; j < 4; ++j) {
      const int col = n0 + wc * 64 + 16 * j + ln;
      const float bvv = bias[col];
      #pragma unroll
      for (int i = 0; i < 4; ++i) {
        const int rowb = m0 + wr * 64 + 16 * i + 4 * quad;
        #pragma unroll
        for (int r = 0; r < 4; ++r)
          vout[(size_t)(rowb + r) * N + col] = acc[i][j][r] + bvv;
      }
    }
  }
}

// ---------------------------------------------------------------------------
// Per-channel circular correlation via 32x32x16 fp16 MFMA + register top-15.
// One block (256 threads, 4 waves) per (b,d) channel.
// r[tau] = sum_t q[t]*k[(t-tau) mod L], tau = 1024p + m + 32n, p in {0,1}
//   A[m,kk] = q[(t0+m+kk)%L]   (8 shifted LDS copies, stride 2072)
//   B_p[kk,n] = k[(t0+kk-1024p-32n)%L]  (doubled ke, immediate offsets)
// 32x32x16 layouts: A[m=lane&31][kk=8*(lane>>5)+j]; B[kk][n=lane&31];
// C/D: col=lane&31 (n), row=(reg&3)+8*(reg>>2)+4*(lane>>5) (m).
// Wave wv covers t-quarter [512*wv, 512*wv+512) for BOTH p (a-frag shared);
// 4 t-partials reduced through the dead qx buffer (swizzled, conflict-free).
// ---------------------------------------------------------------------------
#define QXS3 2072  // row length; covers max offset 24+8+2032+8
__global__ __launch_bounds__(256) void corr_mfma_topk(
    const _Float16* __restrict__ qT, const _Float16* __restrict__ kT,
    float* __restrict__ Wk, int* __restrict__ Ik) {
  __shared__ unsigned short qx[8 * QXS3];  // 33152 B; reused as partial buf
  __shared__ unsigned short ke[4096];      // doubled k, 8 KB
  __shared__ float cv[64];
  __shared__ int ci[64];

  const int tid = threadIdx.x;
  const size_t chan = (size_t)blockIdx.x * Lz;
  const unsigned short* qg = (const unsigned short*)(qT + chan);
  const unsigned short* kg = (const unsigned short*)(kT + chan);

  // ke[i] = k[i mod L], i in [0, 4096)
  for (int c = tid; c < 512; c += 256) {
    ushort8x v = *(const ushort8x*)(kg + ((8 * c) & (Lz - 1)));
    *(ushort8x*)(ke + 8 * c) = v;
  }
  // qx[s][i] = q[(i+s) mod L], i in [0, 2072)
  for (int c = tid; c < QXS3 / 8; c += 256) {
    union { unsigned short u[16]; ushort8x v[2]; } b;
    b.v[0] = *(const ushort8x*)(qg + ((8 * c) & (Lz - 1)));
    b.v[1] = *(const ushort8x*)(qg + ((8 * c + 8) & (Lz - 1)));
    #pragma unroll
    for (int s = 0; s < 8; ++s) {
      ushort8x w;
      #pragma unroll
      for (int t = 0; t < 8; ++t) w[t] = b.u[s + t];
      *(ushort8x*)(qx + s * QXS3 + 8 * c) = w;
    }
  }
  __syncthreads();

  const int lane = tid & 63;
  const int wv = tid >> 6;          // t-quarter
  const int n = lane & 31;
  const int kg5 = lane >> 5;        // k-block selector
  const int s = n & 7;              // A-row shift (row m = lane&31 too)
  const unsigned short* qxs = qx + s * QXS3 + (n & 24) + 8 * kg5;
  const int bb = 2048 + 8 * kg5 - 32 * n;  // p=0 base; p=1 subtract 1024

  floatx16 acc0 = {};
  floatx16 acc1 = {};
  const int t00 = 512 * wv;
  #pragma unroll 4
  for (int t0r = 0; t0r < 512; t0r += 16) {
    const int t0 = t00 + t0r;
    half8x a = *(const half8x*)(qxs + t0);
    half8x b0 = *(const half8x*)(ke + bb + t0);
    half8x b1 = *(const half8x*)(ke + bb - 1024 + t0);
    acc0 = __builtin_amdgcn_mfma_f32_32x32x16_f16(a, b0, acc0, 0, 0, 0);
    acc1 = __builtin_amdgcn_mfma_f32_32x32x16_f16(a, b1, acc1, 0, 0, 0);
  }
  __syncthreads();  // main loop done; qx is dead -> partial buffer

  // partial write: slot (p*4 + wv) of 1024 floats; swizzled addr within row n:
  // addr = 32n + ((m + 4*(n&7)) & 31), m = (reg&3)+8*(reg>>2)+4*kg5
  float* part = (float*)qx;  // 8 * 1024 * 4 = 32768 B <= 33152
  {
    float* p0 = part + (0 * 4 + wv) * 1024 + 32 * n;
    float* p1 = part + (1 * 4 + wv) * 1024 + 32 * n;
    const int rotb = 4 * (n & 7) + 4 * kg5;
    #pragma unroll
    for (int g = 0; g < 4; ++g) {
      const int rot = (8 * g + rotb) & 31;
      floatx4 w0, w1;
      #pragma unroll
      for (int r = 0; r < 4; ++r) { w0[r] = acc0[4 * g + r]; w1[r] = acc1[4 * g + r]; }
      *(floatx4*)(p0 + rot) = w0;
      *(floatx4*)(p1 + rot) = w1;
    }
  }
  __syncthreads();

  // read back: thread owns tau = 8*tid + j; p = tid>>7, n_r = (tid>>2)&31,
  // m0 = (8*tid)&31; two aligned float4 groups with swizzle applied.
  float vals[8];
  {
    const int pr = tid >> 7;
    const int nr = (tid >> 2) & 31;
    const int m0 = (8 * tid) & 31;
    const int rot0 = (m0 + 4 * (nr & 7)) & 31;
    const int rot1 = (m0 + 4 + 4 * (nr & 7)) & 31;
    const float* baseq = part + (pr * 4) * 1024 + 32 * nr;
    floatx4 s0 = {}, s1 = {};
    #pragma unroll
    for (int tq = 0; tq < 4; ++tq) {
      s0 += *(const floatx4*)(baseq + tq * 1024 + rot0);
      s1 += *(const floatx4*)(baseq + tq * 1024 + rot1);
    }
    #pragma unroll
    for (int r = 0; r < 4; ++r) { vals[r] = s0[r]; vals[4 + r] = s1[r]; }
  }

  // --- per-wave top-15 from registers (no barriers), then wave-0 merge ---
  for (int it = 0; it < KTOP; ++it) {
    float bv = vals[0];
    int bj = 0;
    #pragma unroll
    for (int j = 1; j < 8; ++j)
      if (vals[j] > bv) { bv = vals[j]; bj = j; }
    int bi = 8 * tid + bj;
    #pragma unroll
    for (int off = 1; off < 64; off <<= 1) {
      const float ov = __shfl_xor(bv, off, 64);
      const int oi = __shfl_xor(bi, off, 64);
      if (ov > bv || (ov == bv && oi < bi)) { bv = ov; bi = oi; }
    }
    if (lane == it) { cv[wv * KTOP + it] = bv; ci[wv * KTOP + it] = bi; }
    const int rel = bi - 8 * tid;
    #pragma unroll
    for (int j = 0; j < 8; ++j)
      if (rel == j) vals[j] = -3.0e38f;
  }
  __syncthreads();

  if (wv == 0) {
    float v = (lane < 4 * KTOP) ? cv[lane] : -3.0e38f;
    int ix = (lane < 4 * KTOP) ? ci[lane] : 0x7fffffff;
    float gmax = 0.f, esum = 0.f, selv = 0.f;
    int seli = 0;
    for (int it = 0; it < KTOP; ++it) {
      float bv = v;
      int bi = ix;
      #pragma unroll
      for (int off = 1; off < 64; off <<= 1) {
        const float ov = __shfl_xor(bv, off, 64);
        const int oi = __shfl_xor(bi, off, 64);
        if (ov > bv || (ov == bv && oi < bi)) { bv = ov; bi = oi; }
      }
      if (it == 0) gmax = bv;
      esum += expf(bv - gmax);
      if (lane == it) { selv = bv; seli = bi; }
      if (ix == bi) v = -3.0e38f;
    }
    if (lane < KTOP) {
      const size_t ob = (size_t)blockIdx.x * KTOP;
      Wk[ob + lane] = expf(selv - gmax) / esum;
      Ik[ob + lane] = seli;
    }
  }
}

// ---------------------------------------------------------------------------
// Fused gather: out[b,l,d] = sum_k w[b,d,k] * v[b,(l+I[b,d,k]) mod L, d]
// Block = 8 d-channels (stride-2056 fp16 LDS rows, +8 wrap pad); window reads
// via 3x ds_read_b64 + funnel-shift align; out staged through padded LDS.
// ---------------------------------------------------------------------------
#define GSTR 2056  // channel row stride (halfs): 2048 + 8 pad; bank-spread
__global__ __launch_bounds__(256) void gather_fused(
    const float* __restrict__ v, const float* __restrict__ Wk,
    const int* __restrict__ Ik, float* __restrict__ out) {
  __shared__ _Float16 ls[8 * GSTR];  // 32896 B
  __shared__ float os[256 * 9];      // 9216 B
  const int tid = threadIdx.x;
  const int d0 = blockIdx.x * 8;
  const int b = blockIdx.y;
  const float* vb = v + (size_t)b * Lz * Dz;
  float* ob = out + (size_t)b * Lz * Dz;

  for (int it = 0; it < 16; ++it) {
    const int sslot = tid + 256 * it;  // 4096 slots
    const int l = sslot >> 1, c = sslot & 1;
    const float4 v4 = *(const float4*)&vb[(size_t)l * Dz + d0 + 4 * c];
    ls[(4 * c + 0) * GSTR + l] = (_Float16)v4.x;
    ls[(4 * c + 1) * GSTR + l] = (_Float16)v4.y;
    ls[(4 * c + 2) * GSTR + l] = (_Float16)v4.z;
    ls[(4 * c + 3) * GSTR + l] = (_Float16)v4.w;
  }
  if (tid < 64) {  // wrap pad: ls[dl][2048+t] = v[t][dl]
    const int dl = tid >> 3, t = tid & 7;
    ls[dl * GSTR + 2048 + t] = (_Float16)vb[(size_t)t * Dz + d0 + dl];
  }

  const int dl = tid & 7;
  const int lg = tid >> 3;  // [0,32)
  const size_t wb = ((size_t)b * Dz + d0 + dl) * KTOP;
  float wreg[KTOP];
  int ireg[KTOP];
  #pragma unroll
  for (int k = 0; k < KTOP; ++k) {
    wreg[k] = Wk[wb + k];
    ireg[k] = Ik[wb + k];
  }
  __syncthreads();

  const _Float16* lsd = ls + dl * GSTR;
  for (int lt = 0; lt < 8; ++lt) {
    const int lbase = lt * 256 + lg * 8;
    float acc[8] = {0.f, 0.f, 0.f, 0.f, 0.f, 0.f, 0.f, 0.f};
    for (int k = 0; k < KTOP; ++k) {
      const float w = wreg[k];
      const int sidx = (lbase + ireg[k]) & (Lz - 1);
      const int h = sidx & 3;
      const _Float16* bp = lsd + (sidx & ~3);
      const uint2 q0 = *(const uint2*)bp;
      const uint2 q1 = *(const uint2*)(bp + 4);
      const uint2 q2 = *(const uint2*)(bp + 8);
      const int h2 = h >> 1;
      const uint32_t sh = (uint32_t)(h & 1) * 16u;
      const uint32_t e0 = h2 ? q0.y : q0.x;
      const uint32_t e1 = h2 ? q1.x : q0.y;
      const uint32_t e2 = h2 ? q1.y : q1.x;
      const uint32_t e3 = h2 ? q2.x : q1.y;
      const uint32_t e4 = h2 ? q2.y : q2.x;
      const uint32_t o0 = (uint32_t)(((((uint64_t)e1) << 32) | e0) >> sh);
      const uint32_t o1 = (uint32_t)(((((uint64_t)e2) << 32) | e1) >> sh);
      const uint32_t o2 = (uint32_t)(((((uint64_t)e3) << 32) | e2) >> sh);
      const uint32_t o3 = (uint32_t)(((((uint64_t)e4) << 32) | e3) >> sh);
      union { uint32_t u; _Float16 f[2]; } c0, c1, c2, c3;
      c0.u = o0; c1.u = o1; c2.u = o2; c3.u = o3;
      acc[0] += w * (float)c0.f[0];
      acc[1] += w * (float)c0.f[1];
      acc[2] += w * (float)c1.f[0];
      acc[3] += w * (float)c1.f[1];
      acc[4] += w * (float)c2.f[0];
      acc[5] += w * (float)c2.f[1];
      acc[6] += w * (float)c3.f[0];
      acc[7] += w * (float)c3.f[1];
    }
    __syncthreads();  // previous tile's os reads complete
    #pragma unroll
    for (int j = 0; j < 8; ++j) os[(lg * 8 + j) * 9 + dl] = acc[j];
    __syncthreads();
    #pragma unroll
    for (int c2i = 0; c2i < 2; ++c2i) {
      const int sl = tid + 256 * c2i;  // 512 slots
      const int l = sl >> 1, c = sl & 1;
      float4 o;
      o.x = os[l * 9 + 4 * c + 0];
      o.y = os[l * 9 + 4 * c + 1];
      o.z = os[l * 9 + 4 * c + 2];
      o.w = os[l * 9 + 4 * c + 3];
      *(float4*)&ob[(size_t)(lt * 256 + l) * Dz + d0 + 4 * c] = o;
    }
  }
}

// ---------------------------------------------------------------------------
extern "C" void kernel_launch(void* const* d_in, const int* in_sizes, int n_in,
                              void* d_out, int out_size, void* d_ws, size_t ws_size,
                              hipStream_t stream) {
  const float* Q = (const float*)d_in[0];
  const float* K = (const float*)d_in[1];
  const float* V = (const float*)d_in[2];
  const float* WQw = (const float*)d_in[3];
  const float* WQb = (const float*)d_in[4];
  const float* WKw = (const float*)d_in[5];
  const float* WKb = (const float*)d_in[6];
  const float* WVw = (const float*)d_in[7];
  const float* WVb = (const float*)d_in[8];
  float* out = (float*)d_out;

  const size_t CH = (size_t)Bz * Dz;        // 4096
  const size_t NEL = (size_t)Bz * Lz * Dz;  // 8388608
  const int M = Bz * Lz;                    // 16384

  char* ws = (char*)d_ws;
  _Float16* qT = (_Float16*)ws;              // NEL fp16 (B,D,L)
  _Float16* kT = qT + NEL;                   // NEL fp16
  float* vbuf = (float*)(ws + 2 * NEL * 2);  // NEL fp32 (B,L,D)
  char* p = (char*)(vbuf + NEL);
  _Float16* Wt = (_Float16*)p;               // 3 x 512x512 fp16 contiguous
  float* Wk = (float*)(Wt + 3 * (size_t)Dz * Dz);
  int* Ik = (int*)(Wk + CH * KTOP);

  dim3 tr_block(32, 8);

  // weights -> fp16 transposed (N x K), contiguous x3
  wtrans3<<<dim3(16, 16, 3), tr_block, 0, stream>>>(WQw, WKw, WVw, Wt);

  // merged q/k/v GEMM: q,k -> fp16 (B,D,L); v -> fp32 (B,L,D)
  gemm3<<<dim3(Dz / 128, M / 128, 3), dim3(256), 0, stream>>>(
      Q, K, V, Wt, WQb, WKb, WVb, qT, kT, vbuf);

  // correlation (32x32x16 MFMA) + register top-k + softmax per channel
  corr_mfma_topk<<<dim3((unsigned)CH), dim3(256), 0, stream>>>(qT, kT, Wk, Ik);

  // fused gather -> out (B,L,D)
  gather_fused<<<dim3(Dz / 8, Bz), dim3(256), 0, stream>>>(vbuf, Wk, Ik, out);
}